// Round 7
// baseline (2534.961 us; speedup 1.0000x reference)
//
#include <hip/hip_runtime.h>

#define B_ 32
#define S_ 512
#define D_ 1024
#define H_ 16
#define DK_ 64
#define DFF_ 2048
#define L_ 4

typedef __attribute__((ext_vector_type(8))) short short8;
typedef __attribute__((ext_vector_type(4))) float f32x4;
typedef unsigned short u16;
typedef unsigned int u32;
typedef __attribute__((ext_vector_type(4))) u16 u16x4;
typedef __attribute__((ext_vector_type(8))) u16 u16x8;

__device__ __forceinline__ u16 f2bf(float f) {          // round-nearest-even
    u32 u = __float_as_uint(f);
    u = u + 0x7fffu + ((u >> 16) & 1u);
    return (u16)(u >> 16);
}
__device__ __forceinline__ u16 f2bf_t(float f) {        // truncate (cheap, for P)
    return (u16)(__float_as_uint(f) >> 16);
}
__device__ __forceinline__ float bf2f(u16 v) {
    return __uint_as_float(((u32)v) << 16);
}

__device__ __forceinline__ void async16(const u16* g, u16* l) {
    __builtin_amdgcn_global_load_lds((const __attribute__((address_space(1))) u32*)g,
                                     (__attribute__((address_space(3))) u32*)l, 16, 0, 0);
}

// ---------------------------------------------------------------------------
// GEMM: C[M,N] = A[M,K](bf16) @ Bt[N,K]^T(bf16) + bias[N].
// OUTM: 0 = fp32 row-major, 1 = bf16 row-major, 2 = bf16 V^T [b,h,d,s] layout.
// m201-template port (verified round 4): 256x256 tile, BK=64, 8 waves,
// 2 K-tiles/iter, 8 phases/iter, counted vmcnt(8), XCD swizzle.
// ---------------------------------------------------------------------------
#define LGKM0_FENCE                                                            \
    asm volatile("s_waitcnt lgkmcnt(0)" ::: "memory");                         \
    __builtin_amdgcn_sched_barrier(0);

#define MFQ(MQ, NQ, BQ)                                                        \
    __builtin_amdgcn_s_setprio(1);                                             \
    _Pragma("unroll")                                                          \
    for (int r = 0; r < 4; r++) {                                              \
        _Pragma("unroll")                                                      \
        for (int c = 0; c < 2; c++) {                                          \
            _Pragma("unroll")                                                  \
            for (int kf = 0; kf < 2; kf++)                                     \
                acc[(MQ)*4+r][(NQ)*2+c] =                                      \
                    __builtin_amdgcn_mfma_f32_16x16x32_bf16(                   \
                        a[r][kf], BQ[c][kf], acc[(MQ)*4+r][(NQ)*2+c], 0,0,0);  \
        }                                                                      \
    }                                                                          \
    __builtin_amdgcn_s_setprio(0);

#define RD_AQ(CBA, MQ)                                                         \
    _Pragma("unroll")                                                          \
    for (int r = 0; r < 4; r++) {                                              \
        a[r][0] = *(const short8*)&lds[(CBA) + arow + (MQ)*4096 + r*1024 + chv0]; \
        a[r][1] = *(const short8*)&lds[(CBA) + arow + (MQ)*4096 + r*1024 + chv1]; \
    }

#define RD_BQ(DST, CBB, NQ)                                                    \
    _Pragma("unroll")                                                          \
    for (int c = 0; c < 2; c++) {                                              \
        DST[c][0] = *(const short8*)&lds[(CBB) + brow + (NQ)*2048 + c*1024 + chv0]; \
        DST[c][1] = *(const short8*)&lds[(CBB) + brow + (NQ)*2048 + c*1024 + chv1]; \
    }

template<int RELU, int OUTM>
__global__ __launch_bounds__(512, 2)
void gemm256(const u16* __restrict__ A, const u16* __restrict__ Bt,
             const float* __restrict__ bias, void* __restrict__ C,
             int M, int N, int K)
{
    // A: [2 dbuf][256][64] @ 0 ; B: [2 dbuf][256][64] @ 32768 (u16 index)
    __shared__ __align__(16) u16 lds[65536];
    const int t = threadIdx.x;
    const int w = t >> 6, l = t & 63;
    const int lane16 = l & 15, quad = l >> 4;
    const int wm = w >> 2, wn = w & 3;          // wave grid: 2 (M) x 4 (N)

    // bijective XCD swizzle (m204)
    const int gx = gridDim.x;
    const int nwg = gx * gridDim.y;
    const int orig = blockIdx.y * gx + blockIdx.x;
    const int q8 = nwg >> 3, r8 = nwg & 7;
    const int xcd = orig & 7, sidx = orig >> 3;
    const int nid = (xcd < r8 ? xcd * (q8 + 1) : r8 * (q8 + 1) + (xcd - r8) * q8) + sidx;
    const int m0 = (nid / gx) * 256;
    const int n0 = (nid % gx) * 256;

    f32x4 acc[8][4];
#pragma unroll
    for (int i = 0; i < 8; i++)
#pragma unroll
        for (int j = 0; j < 4; j++) acc[i][j] = f32x4{0.f, 0.f, 0.f, 0.f};

    // ---- staging setup (rule #21: linear LDS dest, inverse-swizzled source)
    const int lr = l >> 3;                       // lane row within 8-row chunk
    const int xorcol = ((l & 7) ^ lr) * 8;       // logical k-offset (u16) of lane's chunk
    const int aw8 = (w < 4 ? w * 8 : 128 + (w - 4) * 8);
    const u16* Asrc = A + (size_t)(m0 + aw8 + lr) * K + xorcol;
    const u16* Bsrc = Bt + (size_t)(n0 + w * 8 + lr) * K + xorcol;

    auto stageA = [&](int tile, int q) {
        const int c = tile & 1;
        async16(Asrc + (size_t)(q * 32) * K + (tile << 6),
                &lds[c * 16384 + (aw8 + q * 32) * 64]);
    };
    auto stageB = [&](int tile, int j) {
        const int c = tile & 1;
        async16(Bsrc + (size_t)(j * 64) * K + (tile << 6),
                &lds[32768 + c * 16384 + (j * 64 + w * 8) * 64]);
    };

    // ---- ds_read fragment addressing (swizzled): chunk ^= row&7
    const int chv0 = ((0 + quad) ^ (lane16 & 7)) * 8;    // kf = 0
    const int chv1 = ((4 + quad) ^ (lane16 & 7)) * 8;    // kf = 1
    const int arow = (wm * 128 + lane16) * 64;           // + MQ*4096 + r*1024 + chv
    const int brow = (wn * 64 + lane16) * 64;            // + CBB + NQ*2048 + c*1024

    const int NT = K >> 6;        // even (K in {1024, 2048})
    const int niter = NT >> 1;

    // ---- prologue: tile0 (8 calls, oldest), tile1 (8 calls, stays in flight)
    stageA(0, 0); stageA(0, 1); stageA(0, 2); stageA(0, 3);
    stageB(0, 0); stageB(0, 1); stageB(0, 2); stageB(0, 3);
    stageA(1, 0); stageA(1, 1);
    stageB(1, 0); stageB(1, 1); stageB(1, 2); stageB(1, 3);
    stageA(1, 2); stageA(1, 3);
    asm volatile("s_waitcnt vmcnt(8)" ::: "memory");   // tile 0 fully landed
    __builtin_amdgcn_sched_barrier(0);
    __builtin_amdgcn_s_barrier();

    short8 a[4][2], b0[2][2], b1[2][2];

    for (int it = 0; it < niter; it++) {
        const bool hn = (it + 1 < niter);
        const int e2 = 2 * it + 2, o2 = 2 * it + 3;

        // ---------------- K-tile e = 2*it (buf0) ----------------
        // ph1 (m0,n0)
        RD_AQ(0, 0)
        RD_BQ(b0, 32768, 0)
        asm volatile("s_waitcnt lgkmcnt(8)" ::: "memory");
        __builtin_amdgcn_s_barrier();
        LGKM0_FENCE
        MFQ(0, 0, b0)
        __builtin_amdgcn_s_barrier();
        // ph2 (m0,n1)
        RD_BQ(b1, 32768, 1)
        if (hn) { stageA(e2, 0); stageA(e2, 1); }
        __builtin_amdgcn_s_barrier();
        LGKM0_FENCE
        MFQ(0, 1, b1)
        __builtin_amdgcn_s_barrier();
        // ph3 (m1,n0)
        RD_AQ(0, 1)
        if (hn) { stageB(e2, 0); stageB(e2, 1); }
        __builtin_amdgcn_s_barrier();
        LGKM0_FENCE
        MFQ(1, 0, b0)
        __builtin_amdgcn_s_barrier();
        // ph4 (m1,n1): stage rest of e+2; vmcnt(8) retires ALL of tile o
        if (hn) { stageB(e2, 2); stageB(e2, 3); stageA(e2, 2); stageA(e2, 3); }
        __builtin_amdgcn_s_barrier();
        MFQ(1, 1, b1)
        if (hn) asm volatile("s_waitcnt vmcnt(8)" ::: "memory");
        else    asm volatile("s_waitcnt vmcnt(0)" ::: "memory");
        __builtin_amdgcn_sched_barrier(0);
        __builtin_amdgcn_s_barrier();

        // ---------------- K-tile o = 2*it+1 (buf1) ----------------
        // ph5 (m0,n0)
        RD_AQ(16384, 0)
        RD_BQ(b0, 49152, 0)
        asm volatile("s_waitcnt lgkmcnt(8)" ::: "memory");
        __builtin_amdgcn_s_barrier();
        LGKM0_FENCE
        MFQ(0, 0, b0)
        __builtin_amdgcn_s_barrier();
        // ph6 (m0,n1)
        RD_BQ(b1, 49152, 1)
        if (hn) { stageA(o2, 0); stageA(o2, 1); }
        __builtin_amdgcn_s_barrier();
        LGKM0_FENCE
        MFQ(0, 1, b1)
        __builtin_amdgcn_s_barrier();
        // ph7 (m1,n0)
        RD_AQ(16384, 1)
        if (hn) { stageB(o2, 0); stageB(o2, 1); }
        __builtin_amdgcn_s_barrier();
        LGKM0_FENCE
        MFQ(1, 0, b0)
        __builtin_amdgcn_s_barrier();
        // ph8 (m1,n1): stage rest of o+2; vmcnt(8) retires e+2
        if (hn) { stageB(o2, 2); stageB(o2, 3); stageA(o2, 2); stageA(o2, 3); }
        __builtin_amdgcn_s_barrier();
        MFQ(1, 1, b1)
        if (hn) asm volatile("s_waitcnt vmcnt(8)" ::: "memory");
        __builtin_amdgcn_sched_barrier(0);
        __builtin_amdgcn_s_barrier();
    }

    // ---- epilogue
#pragma unroll
    for (int mi = 0; mi < 8; mi++) {
#pragma unroll
        for (int ni = 0; ni < 4; ni++) {
            int col = n0 + wn * 64 + ni * 16 + lane16;
            float bv = bias[col];
            if (OUTM == 2) {
                int tok0 = m0 + wm * 128 + mi * 16 + quad * 4;
                int bb = tok0 >> 9, s0 = tok0 & 511;
                int hh = col >> 6, dd = col & 63;
                u16x4 pk;
#pragma unroll
                for (int r2 = 0; r2 < 4; r2++) pk[r2] = f2bf(acc[mi][ni][r2] + bv);
                *(u16x4*)&((u16*)C)[(((size_t)bb * H_ + hh) * DK_ + dd) * S_ + s0] = pk;
            } else {
                int row = m0 + wm * 128 + mi * 16 + quad * 4;
#pragma unroll
                for (int r2 = 0; r2 < 4; r2++) {
                    float v = acc[mi][ni][r2] + bv;
                    if (RELU) v = fmaxf(v, 0.f);
                    size_t idx = (size_t)(row + r2) * N + col;
                    if (OUTM == 1) ((u16*)C)[idx] = f2bf(v);
                    else           ((float*)C)[idx] = v;
                }
            }
        }
    }
}

// ---------------------------------------------------------------------------
// Barrier-free transposed flash attention, max-free softmax.
// Balanced complementary band pairs — each wave processes band
// b1 = (pp<<2)|w AND band 15-b1 sequentially: 9 tiles for EVERY wave.
// Grid 1024 = 512 bh x 2 pp; siblings differ by 512 (≡0 mod 8) -> same XCD.
// K register double-buffer via rule-#20-safe textual macro.
// launch_bounds(256,4): 4 blocks/CU -> 16 balanced waves/CU.
// ---------------------------------------------------------------------------
#define ATT_TILE(KC, KN)                                                       \
    {                                                                          \
        const int j0 = jt * 64;                                                \
        const bool diag = (jt == ntiles - 1);                                  \
        f32x4 sacc[4][2];                                                      \
        _Pragma("unroll")                                                      \
        for (int ji = 0; ji < 4; ji++)                                         \
            _Pragma("unroll")                                                  \
            for (int ii = 0; ii < 2; ii++)                                     \
                sacc[ji][ii] = f32x4{0.f, 0.f, 0.f, 0.f};                      \
        _Pragma("unroll")                                                      \
        for (int kf = 0; kf < 2; kf++)                                         \
            _Pragma("unroll")                                                  \
            for (int ji = 0; ji < 4; ji++)                                     \
                _Pragma("unroll")                                              \
                for (int ii = 0; ii < 2; ii++)                                 \
                    sacc[ji][ii] = __builtin_amdgcn_mfma_f32_16x16x32_bf16(    \
                        KC[kf][ji], bq[ii][kf], sacc[ji][ii], 0, 0, 0);        \
        short8 aV[2][4];                                                       \
        _Pragma("unroll")                                                      \
        for (int kf = 0; kf < 2; kf++)                                         \
            _Pragma("unroll")                                                  \
            for (int di = 0; di < 4; di++)                                     \
                aV[kf][di] = *(const short8*)(vb +                             \
                    (size_t)(di * 16 + lane16) * S_ + j0 + kf * 32 + quad * 8);\
        if (!diag) {                                                           \
            _Pragma("unroll")                                                  \
            for (int kf = 0; kf < 2; kf++)                                     \
                _Pragma("unroll")                                              \
                for (int ji = 0; ji < 4; ji++)                                 \
                    KN[kf][ji] = *(const short8*)(kb +                         \
                        (size_t)(j0 + 64 + ji * 16 + lane16) * D_ +            \
                        kf * 32 + quad * 8);                                   \
        }                                                                      \
        _Pragma("unroll")                                                      \
        for (int ii = 0; ii < 2; ii++) {                                       \
            _Pragma("unroll")                                                  \
            for (int ji = 0; ji < 4; ji++) {                                   \
                u16x4 pk;                                                      \
                _Pragma("unroll")                                              \
                for (int r2 = 0; r2 < 4; r2++) {                               \
                    float v = sacc[ji][ii][r2] * SC;                           \
                    if (diag) {                                                \
                        int j = j0 + ji * 16 + quad * 4 + r2;                  \
                        int i = band0 + ii * 16 + lane16;                      \
                        if (j >= i) v = -3e38f;                                \
                    }                                                          \
                    float pv = exp2f(v);                                       \
                    lsum[ii] += pv;                                            \
                    pk[r2] = f2bf_t(pv);                                       \
                }                                                              \
                *(u16x4*)&myP[(ii * 16 + lane16) * 72 + ji * 16 + quad * 4] = pk; \
            }                                                                  \
        }                                                                      \
        short8 pf[2][2];                                                       \
        _Pragma("unroll")                                                      \
        for (int kf = 0; kf < 2; kf++)                                         \
            _Pragma("unroll")                                                  \
            for (int ii = 0; ii < 2; ii++)                                     \
                pf[kf][ii] = *(const short8*)&myP[(ii * 16 + lane16) * 72 +    \
                                                  kf * 32 + quad * 8];         \
        _Pragma("unroll")                                                      \
        for (int kf = 0; kf < 2; kf++)                                         \
            _Pragma("unroll")                                                  \
            for (int di = 0; di < 4; di++)                                     \
                _Pragma("unroll")                                              \
                for (int ii = 0; ii < 2; ii++)                                 \
                    aco[di][ii] = __builtin_amdgcn_mfma_f32_16x16x32_bf16(     \
                        aV[kf][di], pf[kf][ii], aco[di][ii], 0, 0, 0);         \
    }

__global__ __launch_bounds__(256, 4)
void attn_kernel(const u16* __restrict__ qk, const u16* __restrict__ vt,
                 u16* __restrict__ ao)
{
    __shared__ __align__(16) u16 sP[4][32 * 72];
    const int t = threadIdx.x, w = t >> 6, l = t & 63;
    const int lane16 = l & 15, quad = l >> 4;
    // grid 1024: bid = pp*512 + bh; siblings (pp=0/1) differ by 512 ≡ 0 mod 8
    const int bid = blockIdx.x;
    const int pp = bid >> 9;
    const int bh = bid & 511;
    const int b = bh >> 4, h = bh & 15;
    const int bfirst = (pp << 2) | w;           // 0..7
    const u16* kb = qk + (size_t)b * S_ * D_ + h * DK_;
    const u16* vb = vt + (size_t)bh * DK_ * S_;
    u16* aob = ao + (size_t)b * S_ * D_ + h * DK_;
    const float SC = 0.125f * 1.44269504f;  // (1/sqrt(DK)) * log2(e)
    u16* myP = sP[w];

    for (int half = 0; half < 2; half++) {
        const int band = half == 0 ? bfirst : 15 - bfirst;
        const int band0 = band * 32;
        const int ntiles = (band >> 1) + 1;

        short8 bq[2][2];
#pragma unroll
        for (int ii = 0; ii < 2; ii++)
#pragma unroll
            for (int kf = 0; kf < 2; kf++)
                bq[ii][kf] = *(const short8*)(kb +
                    (size_t)(band0 + ii * 16 + lane16) * D_ + kf * 32 + quad * 8);

        f32x4 aco[4][2];
        float lsum[2] = {0.f, 0.f};
#pragma unroll
        for (int di = 0; di < 4; di++)
#pragma unroll
            for (int ii = 0; ii < 2; ii++) aco[di][ii] = f32x4{0.f, 0.f, 0.f, 0.f};

        short8 aKa[2][4], aKb[2][4];
        // preload K tile 0 into aKa
#pragma unroll
        for (int kf = 0; kf < 2; kf++)
#pragma unroll
            for (int ji = 0; ji < 4; ji++)
                aKa[kf][ji] = *(const short8*)(kb + (size_t)(ji * 16 + lane16) * D_ +
                                               kf * 32 + quad * 8);

        int jt = 0;
        for (;;) {
            ATT_TILE(aKa, aKb)
            if (++jt >= ntiles) break;
            ATT_TILE(aKb, aKa)
            if (++jt >= ntiles) break;
        }

        // fold partial denominators across the 4 quads (replicated per i)
#pragma unroll
        for (int ii = 0; ii < 2; ii++) {
            lsum[ii] += __shfl_xor(lsum[ii], 16);
            lsum[ii] += __shfl_xor(lsum[ii], 32);
        }

        // write O (O^T layout: i=lane16, d=quad*4+r2); row 0 zeroed (zero_pad)
#pragma unroll
        for (int ii = 0; ii < 2; ii++) {
            int row = band0 + ii * 16 + lane16;
            float lv = lsum[ii];
            float inv = (row == 0 || !(lv > 0.f)) ? 0.f : 1.f / lv;
#pragma unroll
            for (int di = 0; di < 4; di++) {
                u16x4 o;
#pragma unroll
                for (int r2 = 0; r2 < 4; r2++) o[r2] = f2bf(aco[di][ii][r2] * inv);
                *(u16x4*)&aob[(size_t)row * D_ + di * 16 + quad * 4] = o;
            }
        }
    }
}

// ---------------------------------------------------------------------------
// Fused residual + LayerNorm. (unchanged)
// ---------------------------------------------------------------------------
template<int XBF, int WF32>
__global__ __launch_bounds__(256)
void ln_kernel(const void* __restrict__ xin, const float* __restrict__ addv,
               const float* __restrict__ sc, const float* __restrict__ bi,
               u16* __restrict__ xb_out, float* __restrict__ f32_out)
{
    const int row = blockIdx.x;
    const int t = threadIdx.x;
    const int w = t >> 6, l = t & 63;
    __shared__ float red[8];
    f32x4 a;
    if (XBF) {
        u16x4 raw = ((const u16x4*)xin)[(size_t)row * 256 + t];
#pragma unroll
        for (int j = 0; j < 4; j++) a[j] = bf2f(raw[j]);
    } else {
        a = ((const f32x4*)xin)[(size_t)row * 256 + t];
    }
    f32x4 c = ((const f32x4*)(addv + (size_t)row * D_))[t];
    f32x4 v;
    float s1 = 0.f, s2 = 0.f;
#pragma unroll
    for (int j = 0; j < 4; j++) {
        v[j] = a[j] + c[j];
        s1 += v[j];
        s2 += v[j] * v[j];
    }
#pragma unroll
    for (int off = 32; off > 0; off >>= 1) {
        s1 += __shfl_xor(s1, off);
        s2 += __shfl_xor(s2, off);
    }
    if (l == 0) { red[w * 2] = s1; red[w * 2 + 1] = s2; }
    __syncthreads();
    s1 = red[0] + red[2] + red[4] + red[6];
    s2 = red[1] + red[3] + red[5] + red[7];
    float mean = s1 * (1.f / D_);
    float var = s2 * (1.f / D_) - mean * mean;
    float rstd = rsqrtf(var + 1e-5f);
    f32x4 s4 = ((const f32x4*)sc)[t];
    f32x4 b4 = ((const f32x4*)bi)[t];
    f32x4 o;
    u16x4 ob;
#pragma unroll
    for (int j = 0; j < 4; j++) {
        o[j] = (v[j] - mean) * rstd * s4[j] + b4[j];
        ob[j] = f2bf(o[j]);
    }
    ((u16x4*)(xb_out + (size_t)row * D_))[t] = ob;
    if (WF32) ((f32x4*)(f32_out + (size_t)row * D_))[t] = o;
}

// fp32 -> bf16 convert
__global__ void cvt_kernel(const float* __restrict__ in, u16* __restrict__ out, int n4)
{
    int i = blockIdx.x * blockDim.x + threadIdx.x;
    if (i < n4) {
        f32x4 v = ((const f32x4*)in)[i];
        u16x4 o;
#pragma unroll
        for (int j = 0; j < 4; j++) o[j] = f2bf(v[j]);
        ((u16x4*)out)[i] = o;
    }
}

// W[K,N] fp32 -> WT[N,K] bf16, 64x64 tiles
__device__ __forceinline__ void tconv_body(const float* W, u16* WT, int K, int N,
                                           int bx, int by, int t)
{
    __shared__ float tile[64][65];
    const int n0 = bx * 64, k0 = by * 64;
#pragma unroll
    for (int i = 0; i < 4; i++) {
        int kr = (t >> 4) + i * 16;
        int nc = (t & 15) * 4;
        f32x4 v = *(const f32x4*)&W[(size_t)(k0 + kr) * N + n0 + nc];
        tile[kr][nc] = v[0]; tile[kr][nc + 1] = v[1];
        tile[kr][nc + 2] = v[2]; tile[kr][nc + 3] = v[3];
    }
    __syncthreads();
#pragma unroll
    for (int i = 0; i < 4; i++) {
        int nr = (t >> 4) + i * 16;
        int kc = (t & 15) * 4;
        u16x4 o;
#pragma unroll
        for (int j = 0; j < 4; j++) o[j] = f2bf(tile[kc + j][nr]);
        *(u16x4*)&WT[(size_t)(n0 + nr) * K + k0 + kc] = o;
    }
}

// all 5 per-layer weights in one dispatch: 3*256 + 512 + 512 = 1792 tiles
__global__ __launch_bounds__(256)
void wconv_kernel(const float* __restrict__ Wk, const float* __restrict__ Wv,
                  const float* __restrict__ Wo, const float* __restrict__ W1f,
                  const float* __restrict__ W2f,
                  u16* __restrict__ wk, u16* __restrict__ wv, u16* __restrict__ wo,
                  u16* __restrict__ w1, u16* __restrict__ w2)
{
    const int idx = blockIdx.x;
    const float* W; u16* T; int K, N, bx, by;
    if (idx < 768) {
        int wsel = idx >> 8, t16 = idx & 255;
        W = (wsel == 0) ? Wk : (wsel == 1) ? Wv : Wo;
        T = (wsel == 0) ? wk : (wsel == 1) ? wv : wo;
        K = 1024; N = 1024; bx = t16 & 15; by = t16 >> 4;
    } else if (idx < 1280) {
        int i = idx - 768;
        W = W1f; T = w1; K = 1024; N = 2048; bx = i & 31; by = i >> 5;
    } else {
        int i = idx - 1280;
        W = W2f; T = w2; K = 2048; N = 1024; bx = i & 15; by = i >> 4;
    }
    tconv_body(W, T, K, N, bx, by, threadIdx.x);
}

extern "C" void kernel_launch(void* const* d_in, const int* in_sizes, int n_in,
                              void* d_out, int out_size, void* d_ws, size_t ws_size,
                              hipStream_t stream)
{
    const float* q_embed = (const float*)d_in[0];
    const float* qa_embed = (const float*)d_in[1];
    const float* Wk = (const float*)d_in[2];
    const float* bk = (const float*)d_in[3];
    const float* Wv = (const float*)d_in[4];
    const float* bv = (const float*)d_in[5];
    const float* Wo = (const float*)d_in[6];
    const float* bo = (const float*)d_in[7];
    const float* ln1_s = (const float*)d_in[8];
    const float* ln1_b = (const float*)d_in[9];
    const float* W1 = (const float*)d_in[10];
    const float* b1 = (const float*)d_in[11];
    const float* W2 = (const float*)d_in[12];
    const float* b2 = (const float*)d_in[13];
    const float* ln2_s = (const float*)d_in[14];
    const float* ln2_b = (const float*)d_in[15];
    (void)in_sizes; (void)n_in; (void)out_size;

    char* ws = (char*)d_ws;
    size_t off = 0;
    auto carve = [&](size_t bytes) -> char* {
        char* p = ws + off;
        off += (bytes + 255) & ~(size_t)255;
        return p;
    };
    const size_t NTOK = (size_t)B_ * S_;  // 16384
    u16* wk = (u16*)carve((size_t)D_ * D_ * 2);
    u16* wv = (u16*)carve((size_t)D_ * D_ * 2);
    u16* wo = (u16*)carve((size_t)D_ * D_ * 2);
    u16* w1 = (u16*)carve((size_t)D_ * DFF_ * 2);
    u16* w2 = (u16*)carve((size_t)DFF_ * D_ * 2);
    u16* x = (u16*)carve(NTOK * D_ * 2);           // bf16 residual master
    u16* U12 = (u16*)carve(NTOK * DFF_ * 2);       // [qkb | vbf] then hb
    u16* U3 = (u16*)carve(NTOK * D_ * 2);          // aob (and ybf in overlay mode)
    size_t off_overlay = off;
    u16* ybf_sep = (u16*)carve(NTOK * D_ * 2);
    bool sep = (ws_size >= off);
    if (!sep) off = off_overlay;
    if (ws_size < off) return;

    u16* qkb = U12;
    u16* vbf = U12 + NTOK * D_;   // V^T [b,h,d,s]
    u16* hb = U12;
    u16* aob = U3;
    u16* ybf = sep ? ybf_sep : U3;
    float* of32 = (float*)d_out;  // fp32 scratch: attn-o / ffn2 outputs

    cvt_kernel<<<16384, 256, 0, stream>>>(q_embed, x, (int)(NTOK * D_ / 4));
    if (sep)
        cvt_kernel<<<16384, 256, 0, stream>>>(qa_embed, ybf, (int)(NTOK * D_ / 4));

    const dim3 G1024(4, 64), G2048(8, 64);   // 256x256 output tiles
    for (int lyr = 0; lyr < L_; lyr++) {
        const size_t wsq = (size_t)lyr * D_ * D_;
        const size_t wf1 = (size_t)lyr * D_ * DFF_;
        wconv_kernel<<<1792, 256, 0, stream>>>(Wk + wsq, Wv + wsq, Wo + wsq,
                                               W1 + wf1, W2 + wf1,
                                               wk, wv, wo, w1, w2);
        if (!sep)
            cvt_kernel<<<16384, 256, 0, stream>>>(qa_embed, ybf, (int)(NTOK * D_ / 4));
        // qk = x @ Wk + bk (bf16, row-major; serves as Q and K)
        gemm256<0, 1><<<G1024, 512, 0, stream>>>(x, wk, bk + lyr * D_,
                                                 qkb, (int)NTOK, D_, D_);
        // v = y @ Wv + bv, written directly as V^T [b,h,d,s]
        gemm256<0, 2><<<G1024, 512, 0, stream>>>(ybf, wv, bv + lyr * D_,
                                                 vbf, (int)NTOK, D_, D_);
        // balanced barrier-free transposed causal attention (9 tiles/wave)
        attn_kernel<<<1024, 256, 0, stream>>>(qkb, vbf, aob);
        // o = attn_out @ Wo + bo (fp32 into d_out scratch)
        gemm256<0, 0><<<G1024, 512, 0, stream>>>(aob, wo, bo + lyr * D_,
                                                 of32, (int)NTOK, D_, D_);
        // x = LN1(x + o)
        if (lyr == 0)
            ln_kernel<0, 0><<<(int)NTOK, 256, 0, stream>>>(q_embed, of32,
                ln1_s + lyr * D_, ln1_b + lyr * D_, x, nullptr);
        else
            ln_kernel<1, 0><<<(int)NTOK, 256, 0, stream>>>(x, of32,
                ln1_s + lyr * D_, ln1_b + lyr * D_, x, nullptr);
        // h = relu(x @ W1 + b1)
        gemm256<1, 1><<<G2048, 512, 0, stream>>>(x, w1, b1 + lyr * DFF_,
                                                 hb, (int)NTOK, DFF_, D_);
        // f = h @ W2 + b2 (fp32 into d_out scratch)
        gemm256<0, 0><<<G1024, 512, 0, stream>>>(hb, w2, b2 + lyr * D_,
                                                 of32, (int)NTOK, D_, DFF_);
        // x = LN2(x + f); final layer also writes fp32 d_out
        if (lyr == L_ - 1)
            ln_kernel<1, 1><<<(int)NTOK, 256, 0, stream>>>(x, of32,
                ln2_s + lyr * D_, ln2_b + lyr * D_, x, (float*)d_out);
        else
            ln_kernel<1, 0><<<(int)NTOK, 256, 0, stream>>>(x, of32,
                ln2_s + lyr * D_, ln2_b + lyr * D_, x, nullptr);
    }
}

// Round 8
// 1734.119 us; speedup vs baseline: 1.4618x; 1.4618x over previous
//
#include <hip/hip_runtime.h>

#define B_ 32
#define S_ 512
#define D_ 1024
#define H_ 16
#define DK_ 64
#define DFF_ 2048
#define L_ 4

typedef __attribute__((ext_vector_type(8))) short short8;
typedef __attribute__((ext_vector_type(4))) float f32x4;
typedef unsigned short u16;
typedef unsigned int u32;
typedef __attribute__((ext_vector_type(4))) u16 u16x4;
typedef __attribute__((ext_vector_type(8))) u16 u16x8;

__device__ __forceinline__ u16 f2bf(float f) {          // round-nearest-even
    u32 u = __float_as_uint(f);
    u = u + 0x7fffu + ((u >> 16) & 1u);
    return (u16)(u >> 16);
}
__device__ __forceinline__ u16 f2bf_t(float f) {        // truncate (cheap, for P)
    return (u16)(__float_as_uint(f) >> 16);
}
__device__ __forceinline__ float bf2f(u16 v) {
    return __uint_as_float(((u32)v) << 16);
}

__device__ __forceinline__ void async16(const u16* g, u16* l) {
    __builtin_amdgcn_global_load_lds((const __attribute__((address_space(1))) u32*)g,
                                     (__attribute__((address_space(3))) u32*)l, 16, 0, 0);
}

// ---------------------------------------------------------------------------
// GEMM: C[M,N] = A[M,K](bf16) @ Bt[N,K]^T(bf16) + bias[N].
// OUTM: 0 = fp32 row-major, 1 = bf16 row-major, 2 = bf16 V^T [b,h,d,s] layout.
// m201-template port (verified round 4): 256x256 tile, BK=64, 8 waves,
// 2 K-tiles/iter, 8 phases/iter, counted vmcnt(8), XCD swizzle.
// ---------------------------------------------------------------------------
#define LGKM0_FENCE                                                            \
    asm volatile("s_waitcnt lgkmcnt(0)" ::: "memory");                         \
    __builtin_amdgcn_sched_barrier(0);

#define MFQ(MQ, NQ, BQ)                                                        \
    __builtin_amdgcn_s_setprio(1);                                             \
    _Pragma("unroll")                                                          \
    for (int r = 0; r < 4; r++) {                                              \
        _Pragma("unroll")                                                      \
        for (int c = 0; c < 2; c++) {                                          \
            _Pragma("unroll")                                                  \
            for (int kf = 0; kf < 2; kf++)                                     \
                acc[(MQ)*4+r][(NQ)*2+c] =                                      \
                    __builtin_amdgcn_mfma_f32_16x16x32_bf16(                   \
                        a[r][kf], BQ[c][kf], acc[(MQ)*4+r][(NQ)*2+c], 0,0,0);  \
        }                                                                      \
    }                                                                          \
    __builtin_amdgcn_s_setprio(0);

#define RD_AQ(CBA, MQ)                                                         \
    _Pragma("unroll")                                                          \
    for (int r = 0; r < 4; r++) {                                              \
        a[r][0] = *(const short8*)&lds[(CBA) + arow + (MQ)*4096 + r*1024 + chv0]; \
        a[r][1] = *(const short8*)&lds[(CBA) + arow + (MQ)*4096 + r*1024 + chv1]; \
    }

#define RD_BQ(DST, CBB, NQ)                                                    \
    _Pragma("unroll")                                                          \
    for (int c = 0; c < 2; c++) {                                              \
        DST[c][0] = *(const short8*)&lds[(CBB) + brow + (NQ)*2048 + c*1024 + chv0]; \
        DST[c][1] = *(const short8*)&lds[(CBB) + brow + (NQ)*2048 + c*1024 + chv1]; \
    }

template<int RELU, int OUTM>
__global__ __launch_bounds__(512, 2)
void gemm256(const u16* __restrict__ A, const u16* __restrict__ Bt,
             const float* __restrict__ bias, void* __restrict__ C,
             int M, int N, int K)
{
    // A: [2 dbuf][256][64] @ 0 ; B: [2 dbuf][256][64] @ 32768 (u16 index)
    __shared__ __align__(16) u16 lds[65536];
    const int t = threadIdx.x;
    const int w = t >> 6, l = t & 63;
    const int lane16 = l & 15, quad = l >> 4;
    const int wm = w >> 2, wn = w & 3;          // wave grid: 2 (M) x 4 (N)

    // bijective XCD swizzle (m204)
    const int gx = gridDim.x;
    const int nwg = gx * gridDim.y;
    const int orig = blockIdx.y * gx + blockIdx.x;
    const int q8 = nwg >> 3, r8 = nwg & 7;
    const int xcd = orig & 7, sidx = orig >> 3;
    const int nid = (xcd < r8 ? xcd * (q8 + 1) : r8 * (q8 + 1) + (xcd - r8) * q8) + sidx;
    const int m0 = (nid / gx) * 256;
    const int n0 = (nid % gx) * 256;

    f32x4 acc[8][4];
#pragma unroll
    for (int i = 0; i < 8; i++)
#pragma unroll
        for (int j = 0; j < 4; j++) acc[i][j] = f32x4{0.f, 0.f, 0.f, 0.f};

    // ---- staging setup (rule #21: linear LDS dest, inverse-swizzled source)
    const int lr = l >> 3;                       // lane row within 8-row chunk
    const int xorcol = ((l & 7) ^ lr) * 8;       // logical k-offset (u16) of lane's chunk
    const int aw8 = (w < 4 ? w * 8 : 128 + (w - 4) * 8);
    const u16* Asrc = A + (size_t)(m0 + aw8 + lr) * K + xorcol;
    const u16* Bsrc = Bt + (size_t)(n0 + w * 8 + lr) * K + xorcol;

    auto stageA = [&](int tile, int q) {
        const int c = tile & 1;
        async16(Asrc + (size_t)(q * 32) * K + (tile << 6),
                &lds[c * 16384 + (aw8 + q * 32) * 64]);
    };
    auto stageB = [&](int tile, int j) {
        const int c = tile & 1;
        async16(Bsrc + (size_t)(j * 64) * K + (tile << 6),
                &lds[32768 + c * 16384 + (j * 64 + w * 8) * 64]);
    };

    // ---- ds_read fragment addressing (swizzled): chunk ^= row&7
    const int chv0 = ((0 + quad) ^ (lane16 & 7)) * 8;    // kf = 0
    const int chv1 = ((4 + quad) ^ (lane16 & 7)) * 8;    // kf = 1
    const int arow = (wm * 128 + lane16) * 64;           // + MQ*4096 + r*1024 + chv
    const int brow = (wn * 64 + lane16) * 64;            // + CBB + NQ*2048 + c*1024

    const int NT = K >> 6;        // even (K in {1024, 2048})
    const int niter = NT >> 1;

    // ---- prologue: tile0 (8 calls, oldest), tile1 (8 calls, stays in flight)
    stageA(0, 0); stageA(0, 1); stageA(0, 2); stageA(0, 3);
    stageB(0, 0); stageB(0, 1); stageB(0, 2); stageB(0, 3);
    stageA(1, 0); stageA(1, 1);
    stageB(1, 0); stageB(1, 1); stageB(1, 2); stageB(1, 3);
    stageA(1, 2); stageA(1, 3);
    asm volatile("s_waitcnt vmcnt(8)" ::: "memory");   // tile 0 fully landed
    __builtin_amdgcn_sched_barrier(0);
    __builtin_amdgcn_s_barrier();

    short8 a[4][2], b0[2][2], b1[2][2];

    for (int it = 0; it < niter; it++) {
        const bool hn = (it + 1 < niter);
        const int e2 = 2 * it + 2, o2 = 2 * it + 3;

        // ---------------- K-tile e = 2*it (buf0) ----------------
        // ph1 (m0,n0)
        RD_AQ(0, 0)
        RD_BQ(b0, 32768, 0)
        asm volatile("s_waitcnt lgkmcnt(8)" ::: "memory");
        __builtin_amdgcn_s_barrier();
        LGKM0_FENCE
        MFQ(0, 0, b0)
        __builtin_amdgcn_s_barrier();
        // ph2 (m0,n1)
        RD_BQ(b1, 32768, 1)
        if (hn) { stageA(e2, 0); stageA(e2, 1); }
        __builtin_amdgcn_s_barrier();
        LGKM0_FENCE
        MFQ(0, 1, b1)
        __builtin_amdgcn_s_barrier();
        // ph3 (m1,n0)
        RD_AQ(0, 1)
        if (hn) { stageB(e2, 0); stageB(e2, 1); }
        __builtin_amdgcn_s_barrier();
        LGKM0_FENCE
        MFQ(1, 0, b0)
        __builtin_amdgcn_s_barrier();
        // ph4 (m1,n1): stage rest of e+2; vmcnt(8) retires ALL of tile o
        if (hn) { stageB(e2, 2); stageB(e2, 3); stageA(e2, 2); stageA(e2, 3); }
        __builtin_amdgcn_s_barrier();
        MFQ(1, 1, b1)
        if (hn) asm volatile("s_waitcnt vmcnt(8)" ::: "memory");
        else    asm volatile("s_waitcnt vmcnt(0)" ::: "memory");
        __builtin_amdgcn_sched_barrier(0);
        __builtin_amdgcn_s_barrier();

        // ---------------- K-tile o = 2*it+1 (buf1) ----------------
        // ph5 (m0,n0)
        RD_AQ(16384, 0)
        RD_BQ(b0, 49152, 0)
        asm volatile("s_waitcnt lgkmcnt(8)" ::: "memory");
        __builtin_amdgcn_s_barrier();
        LGKM0_FENCE
        MFQ(0, 0, b0)
        __builtin_amdgcn_s_barrier();
        // ph6 (m0,n1)
        RD_BQ(b1, 49152, 1)
        if (hn) { stageA(o2, 0); stageA(o2, 1); }
        __builtin_amdgcn_s_barrier();
        LGKM0_FENCE
        MFQ(0, 1, b1)
        __builtin_amdgcn_s_barrier();
        // ph7 (m1,n0)
        RD_AQ(16384, 1)
        if (hn) { stageB(o2, 0); stageB(o2, 1); }
        __builtin_amdgcn_s_barrier();
        LGKM0_FENCE
        MFQ(1, 0, b0)
        __builtin_amdgcn_s_barrier();
        // ph8 (m1,n1): stage rest of o+2; vmcnt(8) retires e+2
        if (hn) { stageB(o2, 2); stageB(o2, 3); stageA(o2, 2); stageA(o2, 3); }
        __builtin_amdgcn_s_barrier();
        MFQ(1, 1, b1)
        if (hn) asm volatile("s_waitcnt vmcnt(8)" ::: "memory");
        __builtin_amdgcn_sched_barrier(0);
        __builtin_amdgcn_s_barrier();
    }

    // ---- epilogue
#pragma unroll
    for (int mi = 0; mi < 8; mi++) {
#pragma unroll
        for (int ni = 0; ni < 4; ni++) {
            int col = n0 + wn * 64 + ni * 16 + lane16;
            float bv = bias[col];
            if (OUTM == 2) {
                int tok0 = m0 + wm * 128 + mi * 16 + quad * 4;
                int bb = tok0 >> 9, s0 = tok0 & 511;
                int hh = col >> 6, dd = col & 63;
                u16x4 pk;
#pragma unroll
                for (int r2 = 0; r2 < 4; r2++) pk[r2] = f2bf(acc[mi][ni][r2] + bv);
                *(u16x4*)&((u16*)C)[(((size_t)bb * H_ + hh) * DK_ + dd) * S_ + s0] = pk;
            } else {
                int row = m0 + wm * 128 + mi * 16 + quad * 4;
#pragma unroll
                for (int r2 = 0; r2 < 4; r2++) {
                    float v = acc[mi][ni][r2] + bv;
                    if (RELU) v = fmaxf(v, 0.f);
                    size_t idx = (size_t)(row + r2) * N + col;
                    if (OUTM == 1) ((u16*)C)[idx] = f2bf(v);
                    else           ((float*)C)[idx] = v;
                }
            }
        }
    }
}

// ---------------------------------------------------------------------------
// Barrier-free transposed flash attention, max-free softmax.
// Balanced complementary band pairs — each wave processes band
// b1 = (pp<<2)|w AND band 15-b1 sequentially: 9 tiles for EVERY wave.
// Grid 1024 = 512 bh x 2 pp; siblings differ by 512 (≡0 mod 8) -> same XCD.
// K register double-buffer via rule-#20-safe textual macro.
// FIX vs round 7: launch_bounds (256,2) — the (256,4) hint capped the
// allocator at 128 VGPR and spilled everything (VGPR 64, 1.0 GB scratch
// traffic, 263 us). (256,2) allows 256 VGPR; round-5 body allocated 116
// under the same bound. If VGPR lands <=128, HW still runs 4 waves/SIMD.
// ---------------------------------------------------------------------------
#define ATT_TILE(KC, KN)                                                       \
    {                                                                          \
        const int j0 = jt * 64;                                                \
        const bool diag = (jt == ntiles - 1);                                  \
        f32x4 sacc[4][2];                                                      \
        _Pragma("unroll")                                                      \
        for (int ji = 0; ji < 4; ji++)                                         \
            _Pragma("unroll")                                                  \
            for (int ii = 0; ii < 2; ii++)                                     \
                sacc[ji][ii] = f32x4{0.f, 0.f, 0.f, 0.f};                      \
        _Pragma("unroll")                                                      \
        for (int kf = 0; kf < 2; kf++)                                         \
            _Pragma("unroll")                                                  \
            for (int ji = 0; ji < 4; ji++)                                     \
                _Pragma("unroll")                                              \
                for (int ii = 0; ii < 2; ii++)                                 \
                    sacc[ji][ii] = __builtin_amdgcn_mfma_f32_16x16x32_bf16(    \
                        KC[kf][ji], bq[ii][kf], sacc[ji][ii], 0, 0, 0);        \
        short8 aV[2][4];                                                       \
        _Pragma("unroll")                                                      \
        for (int kf = 0; kf < 2; kf++)                                         \
            _Pragma("unroll")                                                  \
            for (int di = 0; di < 4; di++)                                     \
                aV[kf][di] = *(const short8*)(vb +                             \
                    (size_t)(di * 16 + lane16) * S_ + j0 + kf * 32 + quad * 8);\
        if (!diag) {                                                           \
            _Pragma("unroll")                                                  \
            for (int kf = 0; kf < 2; kf++)                                     \
                _Pragma("unroll")                                              \
                for (int ji = 0; ji < 4; ji++)                                 \
                    KN[kf][ji] = *(const short8*)(kb +                         \
                        (size_t)(j0 + 64 + ji * 16 + lane16) * D_ +            \
                        kf * 32 + quad * 8);                                   \
        }                                                                      \
        _Pragma("unroll")                                                      \
        for (int ii = 0; ii < 2; ii++) {                                       \
            _Pragma("unroll")                                                  \
            for (int ji = 0; ji < 4; ji++) {                                   \
                u16x4 pk;                                                      \
                _Pragma("unroll")                                              \
                for (int r2 = 0; r2 < 4; r2++) {                               \
                    float v = sacc[ji][ii][r2] * SC;                           \
                    if (diag) {                                                \
                        int j = j0 + ji * 16 + quad * 4 + r2;                  \
                        int i = band0 + ii * 16 + lane16;                      \
                        if (j >= i) v = -3e38f;                                \
                    }                                                          \
                    float pv = exp2f(v);                                       \
                    lsum[ii] += pv;                                            \
                    pk[r2] = f2bf_t(pv);                                       \
                }                                                              \
                *(u16x4*)&myP[(ii * 16 + lane16) * 72 + ji * 16 + quad * 4] = pk; \
            }                                                                  \
        }                                                                      \
        short8 pf[2][2];                                                       \
        _Pragma("unroll")                                                      \
        for (int kf = 0; kf < 2; kf++)                                         \
            _Pragma("unroll")                                                  \
            for (int ii = 0; ii < 2; ii++)                                     \
                pf[kf][ii] = *(const short8*)&myP[(ii * 16 + lane16) * 72 +    \
                                                  kf * 32 + quad * 8];         \
        _Pragma("unroll")                                                      \
        for (int kf = 0; kf < 2; kf++)                                         \
            _Pragma("unroll")                                                  \
            for (int di = 0; di < 4; di++)                                     \
                _Pragma("unroll")                                              \
                for (int ii = 0; ii < 2; ii++)                                 \
                    aco[di][ii] = __builtin_amdgcn_mfma_f32_16x16x32_bf16(     \
                        aV[kf][di], pf[kf][ii], aco[di][ii], 0, 0, 0);         \
    }

__global__ __launch_bounds__(256, 2)
void attn_kernel(const u16* __restrict__ qk, const u16* __restrict__ vt,
                 u16* __restrict__ ao)
{
    __shared__ __align__(16) u16 sP[4][32 * 72];
    const int t = threadIdx.x, w = t >> 6, l = t & 63;
    const int lane16 = l & 15, quad = l >> 4;
    // grid 1024: bid = pp*512 + bh; siblings (pp=0/1) differ by 512 ≡ 0 mod 8
    const int bid = blockIdx.x;
    const int pp = bid >> 9;
    const int bh = bid & 511;
    const int b = bh >> 4, h = bh & 15;
    const int bfirst = (pp << 2) | w;           // 0..7
    const u16* kb = qk + (size_t)b * S_ * D_ + h * DK_;
    const u16* vb = vt + (size_t)bh * DK_ * S_;
    u16* aob = ao + (size_t)b * S_ * D_ + h * DK_;
    const float SC = 0.125f * 1.44269504f;  // (1/sqrt(DK)) * log2(e)
    u16* myP = sP[w];

    for (int half = 0; half < 2; half++) {
        const int band = half == 0 ? bfirst : 15 - bfirst;
        const int band0 = band * 32;
        const int ntiles = (band >> 1) + 1;

        short8 bq[2][2];
#pragma unroll
        for (int ii = 0; ii < 2; ii++)
#pragma unroll
            for (int kf = 0; kf < 2; kf++)
                bq[ii][kf] = *(const short8*)(kb +
                    (size_t)(band0 + ii * 16 + lane16) * D_ + kf * 32 + quad * 8);

        f32x4 aco[4][2];
        float lsum[2] = {0.f, 0.f};
#pragma unroll
        for (int di = 0; di < 4; di++)
#pragma unroll
            for (int ii = 0; ii < 2; ii++) aco[di][ii] = f32x4{0.f, 0.f, 0.f, 0.f};

        short8 aKa[2][4], aKb[2][4];
        // preload K tile 0 into aKa
#pragma unroll
        for (int kf = 0; kf < 2; kf++)
#pragma unroll
            for (int ji = 0; ji < 4; ji++)
                aKa[kf][ji] = *(const short8*)(kb + (size_t)(ji * 16 + lane16) * D_ +
                                               kf * 32 + quad * 8);

        int jt = 0;
        for (;;) {
            ATT_TILE(aKa, aKb)
            if (++jt >= ntiles) break;
            ATT_TILE(aKb, aKa)
            if (++jt >= ntiles) break;
        }

        // fold partial denominators across the 4 quads (replicated per i)
#pragma unroll
        for (int ii = 0; ii < 2; ii++) {
            lsum[ii] += __shfl_xor(lsum[ii], 16);
            lsum[ii] += __shfl_xor(lsum[ii], 32);
        }

        // write O (O^T layout: i=lane16, d=quad*4+r2); row 0 zeroed (zero_pad)
#pragma unroll
        for (int ii = 0; ii < 2; ii++) {
            int row = band0 + ii * 16 + lane16;
            float lv = lsum[ii];
            float inv = (row == 0 || !(lv > 0.f)) ? 0.f : 1.f / lv;
#pragma unroll
            for (int di = 0; di < 4; di++) {
                u16x4 o;
#pragma unroll
                for (int r2 = 0; r2 < 4; r2++) o[r2] = f2bf(aco[di][ii][r2] * inv);
                *(u16x4*)&aob[(size_t)row * D_ + di * 16 + quad * 4] = o;
            }
        }
    }
}

// ---------------------------------------------------------------------------
// Fused residual + LayerNorm. (unchanged)
// ---------------------------------------------------------------------------
template<int XBF, int WF32>
__global__ __launch_bounds__(256)
void ln_kernel(const void* __restrict__ xin, const float* __restrict__ addv,
               const float* __restrict__ sc, const float* __restrict__ bi,
               u16* __restrict__ xb_out, float* __restrict__ f32_out)
{
    const int row = blockIdx.x;
    const int t = threadIdx.x;
    const int w = t >> 6, l = t & 63;
    __shared__ float red[8];
    f32x4 a;
    if (XBF) {
        u16x4 raw = ((const u16x4*)xin)[(size_t)row * 256 + t];
#pragma unroll
        for (int j = 0; j < 4; j++) a[j] = bf2f(raw[j]);
    } else {
        a = ((const f32x4*)xin)[(size_t)row * 256 + t];
    }
    f32x4 c = ((const f32x4*)(addv + (size_t)row * D_))[t];
    f32x4 v;
    float s1 = 0.f, s2 = 0.f;
#pragma unroll
    for (int j = 0; j < 4; j++) {
        v[j] = a[j] + c[j];
        s1 += v[j];
        s2 += v[j] * v[j];
    }
#pragma unroll
    for (int off = 32; off > 0; off >>= 1) {
        s1 += __shfl_xor(s1, off);
        s2 += __shfl_xor(s2, off);
    }
    if (l == 0) { red[w * 2] = s1; red[w * 2 + 1] = s2; }
    __syncthreads();
    s1 = red[0] + red[2] + red[4] + red[6];
    s2 = red[1] + red[3] + red[5] + red[7];
    float mean = s1 * (1.f / D_);
    float var = s2 * (1.f / D_) - mean * mean;
    float rstd = rsqrtf(var + 1e-5f);
    f32x4 s4 = ((const f32x4*)sc)[t];
    f32x4 b4 = ((const f32x4*)bi)[t];
    f32x4 o;
    u16x4 ob;
#pragma unroll
    for (int j = 0; j < 4; j++) {
        o[j] = (v[j] - mean) * rstd * s4[j] + b4[j];
        ob[j] = f2bf(o[j]);
    }
    ((u16x4*)(xb_out + (size_t)row * D_))[t] = ob;
    if (WF32) ((f32x4*)(f32_out + (size_t)row * D_))[t] = o;
}

// fp32 -> bf16 convert
__global__ void cvt_kernel(const float* __restrict__ in, u16* __restrict__ out, int n4)
{
    int i = blockIdx.x * blockDim.x + threadIdx.x;
    if (i < n4) {
        f32x4 v = ((const f32x4*)in)[i];
        u16x4 o;
#pragma unroll
        for (int j = 0; j < 4; j++) o[j] = f2bf(v[j]);
        ((u16x4*)out)[i] = o;
    }
}

// W[K,N] fp32 -> WT[N,K] bf16, 64x64 tiles
__device__ __forceinline__ void tconv_body(const float* W, u16* WT, int K, int N,
                                           int bx, int by, int t)
{
    __shared__ float tile[64][65];
    const int n0 = bx * 64, k0 = by * 64;
#pragma unroll
    for (int i = 0; i < 4; i++) {
        int kr = (t >> 4) + i * 16;
        int nc = (t & 15) * 4;
        f32x4 v = *(const f32x4*)&W[(size_t)(k0 + kr) * N + n0 + nc];
        tile[kr][nc] = v[0]; tile[kr][nc + 1] = v[1];
        tile[kr][nc + 2] = v[2]; tile[kr][nc + 3] = v[3];
    }
    __syncthreads();
#pragma unroll
    for (int i = 0; i < 4; i++) {
        int nr = (t >> 4) + i * 16;
        int kc = (t & 15) * 4;
        u16x4 o;
#pragma unroll
        for (int j = 0; j < 4; j++) o[j] = f2bf(tile[kc + j][nr]);
        *(u16x4*)&WT[(size_t)(n0 + nr) * K + k0 + kc] = o;
    }
}

// all 5 per-layer weights in one dispatch: 3*256 + 512 + 512 = 1792 tiles
__global__ __launch_bounds__(256)
void wconv_kernel(const float* __restrict__ Wk, const float* __restrict__ Wv,
                  const float* __restrict__ Wo, const float* __restrict__ W1f,
                  const float* __restrict__ W2f,
                  u16* __restrict__ wk, u16* __restrict__ wv, u16* __restrict__ wo,
                  u16* __restrict__ w1, u16* __restrict__ w2)
{
    const int idx = blockIdx.x;
    const float* W; u16* T; int K, N, bx, by;
    if (idx < 768) {
        int wsel = idx >> 8, t16 = idx & 255;
        W = (wsel == 0) ? Wk : (wsel == 1) ? Wv : Wo;
        T = (wsel == 0) ? wk : (wsel == 1) ? wv : wo;
        K = 1024; N = 1024; bx = t16 & 15; by = t16 >> 4;
    } else if (idx < 1280) {
        int i = idx - 768;
        W = W1f; T = w1; K = 1024; N = 2048; bx = i & 31; by = i >> 5;
    } else {
        int i = idx - 1280;
        W = W2f; T = w2; K = 2048; N = 1024; bx = i & 15; by = i >> 4;
    }
    tconv_body(W, T, K, N, bx, by, threadIdx.x);
}

extern "C" void kernel_launch(void* const* d_in, const int* in_sizes, int n_in,
                              void* d_out, int out_size, void* d_ws, size_t ws_size,
                              hipStream_t stream)
{
    const float* q_embed = (const float*)d_in[0];
    const float* qa_embed = (const float*)d_in[1];
    const float* Wk = (const float*)d_in[2];
    const float* bk = (const float*)d_in[3];
    const float* Wv = (const float*)d_in[4];
    const float* bv = (const float*)d_in[5];
    const float* Wo = (const float*)d_in[6];
    const float* bo = (const float*)d_in[7];
    const float* ln1_s = (const float*)d_in[8];
    const float* ln1_b = (const float*)d_in[9];
    const float* W1 = (const float*)d_in[10];
    const float* b1 = (const float*)d_in[11];
    const float* W2 = (const float*)d_in[12];
    const float* b2 = (const float*)d_in[13];
    const float* ln2_s = (const float*)d_in[14];
    const float* ln2_b = (const float*)d_in[15];
    (void)in_sizes; (void)n_in; (void)out_size;

    char* ws = (char*)d_ws;
    size_t off = 0;
    auto carve = [&](size_t bytes) -> char* {
        char* p = ws + off;
        off += (bytes + 255) & ~(size_t)255;
        return p;
    };
    const size_t NTOK = (size_t)B_ * S_;  // 16384
    u16* wk = (u16*)carve((size_t)D_ * D_ * 2);
    u16* wv = (u16*)carve((size_t)D_ * D_ * 2);
    u16* wo = (u16*)carve((size_t)D_ * D_ * 2);
    u16* w1 = (u16*)carve((size_t)D_ * DFF_ * 2);
    u16* w2 = (u16*)carve((size_t)DFF_ * D_ * 2);
    u16* x = (u16*)carve(NTOK * D_ * 2);           // bf16 residual master
    u16* U12 = (u16*)carve(NTOK * DFF_ * 2);       // [qkb | vbf] then hb
    u16* U3 = (u16*)carve(NTOK * D_ * 2);          // aob (and ybf in overlay mode)
    size_t off_overlay = off;
    u16* ybf_sep = (u16*)carve(NTOK * D_ * 2);
    bool sep = (ws_size >= off);
    if (!sep) off = off_overlay;
    if (ws_size < off) return;

    u16* qkb = U12;
    u16* vbf = U12 + NTOK * D_;   // V^T [b,h,d,s]
    u16* hb = U12;
    u16* aob = U3;
    u16* ybf = sep ? ybf_sep : U3;
    float* of32 = (float*)d_out;  // fp32 scratch: attn-o / ffn2 outputs

    cvt_kernel<<<16384, 256, 0, stream>>>(q_embed, x, (int)(NTOK * D_ / 4));
    if (sep)
        cvt_kernel<<<16384, 256, 0, stream>>>(qa_embed, ybf, (int)(NTOK * D_ / 4));

    const dim3 G1024(4, 64), G2048(8, 64);   // 256x256 output tiles
    for (int lyr = 0; lyr < L_; lyr++) {
        const size_t wsq = (size_t)lyr * D_ * D_;
        const size_t wf1 = (size_t)lyr * D_ * DFF_;
        wconv_kernel<<<1792, 256, 0, stream>>>(Wk + wsq, Wv + wsq, Wo + wsq,
                                               W1 + wf1, W2 + wf1,
                                               wk, wv, wo, w1, w2);
        if (!sep)
            cvt_kernel<<<16384, 256, 0, stream>>>(qa_embed, ybf, (int)(NTOK * D_ / 4));
        // qk = x @ Wk + bk (bf16, row-major; serves as Q and K)
        gemm256<0, 1><<<G1024, 512, 0, stream>>>(x, wk, bk + lyr * D_,
                                                 qkb, (int)NTOK, D_, D_);
        // v = y @ Wv + bv, written directly as V^T [b,h,d,s]
        gemm256<0, 2><<<G1024, 512, 0, stream>>>(ybf, wv, bv + lyr * D_,
                                                 vbf, (int)NTOK, D_, D_);
        // balanced barrier-free transposed causal attention (9 tiles/wave)
        attn_kernel<<<1024, 256, 0, stream>>>(qkb, vbf, aob);
        // o = attn_out @ Wo + bo (fp32 into d_out scratch)
        gemm256<0, 0><<<G1024, 512, 0, stream>>>(aob, wo, bo + lyr * D_,
                                                 of32, (int)NTOK, D_, D_);
        // x = LN1(x + o)
        if (lyr == 0)
            ln_kernel<0, 0><<<(int)NTOK, 256, 0, stream>>>(q_embed, of32,
                ln1_s + lyr * D_, ln1_b + lyr * D_, x, nullptr);
        else
            ln_kernel<1, 0><<<(int)NTOK, 256, 0, stream>>>(x, of32,
                ln1_s + lyr * D_, ln1_b + lyr * D_, x, nullptr);
        // h = relu(x @ W1 + b1)
        gemm256<1, 1><<<G2048, 512, 0, stream>>>(x, w1, b1 + lyr * DFF_,
                                                 hb, (int)NTOK, DFF_, D_);
        // f = h @ W2 + b2 (fp32 into d_out scratch)
        gemm256<0, 0><<<G1024, 512, 0, stream>>>(hb, w2, b2 + lyr * D_,
                                                 of32, (int)NTOK, D_, DFF_);
        // x = LN2(x + f); final layer also writes fp32 d_out
        if (lyr == L_ - 1)
            ln_kernel<1, 1><<<(int)NTOK, 256, 0, stream>>>(x, of32,
                ln2_s + lyr * D_, ln2_b + lyr * D_, x, (float*)d_out);
        else
            ln_kernel<1, 0><<<(int)NTOK, 256, 0, stream>>>(x, of32,
                ln2_s + lyr * D_, ln2_b + lyr * D_, x, nullptr);
    }
}

// Round 9
// 1729.552 us; speedup vs baseline: 1.4657x; 1.0026x over previous
//
#include <hip/hip_runtime.h>

#define B_ 32
#define S_ 512
#define D_ 1024
#define H_ 16
#define DK_ 64
#define DFF_ 2048
#define L_ 4

typedef __attribute__((ext_vector_type(8))) short short8;
typedef __attribute__((ext_vector_type(4))) float f32x4;
typedef unsigned short u16;
typedef unsigned int u32;
typedef __attribute__((ext_vector_type(4))) u16 u16x4;
typedef __attribute__((ext_vector_type(8))) u16 u16x8;

__device__ __forceinline__ u16 f2bf(float f) {          // round-nearest-even
    u32 u = __float_as_uint(f);
    u = u + 0x7fffu + ((u >> 16) & 1u);
    return (u16)(u >> 16);
}
__device__ __forceinline__ u16 f2bf_t(float f) {        // truncate (cheap, for P)
    return (u16)(__float_as_uint(f) >> 16);
}
__device__ __forceinline__ float bf2f(u16 v) {
    return __uint_as_float(((u32)v) << 16);
}

__device__ __forceinline__ void async16(const u16* g, u16* l) {
    __builtin_amdgcn_global_load_lds((const __attribute__((address_space(1))) u32*)g,
                                     (__attribute__((address_space(3))) u32*)l, 16, 0, 0);
}

// ---------------------------------------------------------------------------
// GEMM: C[M,N] = A[M,K](bf16) @ Bt[N,K]^T(bf16) + bias[N].
// OUTM: 0 = fp32 row-major, 1 = bf16 row-major, 2 = bf16 V^T [b,h,d,s] layout.
// m201-template port (verified round 4): 256x256 tile, BK=64, 8 waves,
// 2 K-tiles/iter, 8 phases/iter, counted vmcnt(8), XCD swizzle. UNCHANGED.
// ---------------------------------------------------------------------------
#define LGKM0_FENCE                                                            \
    asm volatile("s_waitcnt lgkmcnt(0)" ::: "memory");                         \
    __builtin_amdgcn_sched_barrier(0);

#define MFQ(MQ, NQ, BQ)                                                        \
    __builtin_amdgcn_s_setprio(1);                                             \
    _Pragma("unroll")                                                          \
    for (int r = 0; r < 4; r++) {                                              \
        _Pragma("unroll")                                                      \
        for (int c = 0; c < 2; c++) {                                          \
            _Pragma("unroll")                                                  \
            for (int kf = 0; kf < 2; kf++)                                     \
                acc[(MQ)*4+r][(NQ)*2+c] =                                      \
                    __builtin_amdgcn_mfma_f32_16x16x32_bf16(                   \
                        a[r][kf], BQ[c][kf], acc[(MQ)*4+r][(NQ)*2+c], 0,0,0);  \
        }                                                                      \
    }                                                                          \
    __builtin_amdgcn_s_setprio(0);

#define RD_AQ(CBA, MQ)                                                         \
    _Pragma("unroll")                                                          \
    for (int r = 0; r < 4; r++) {                                              \
        a[r][0] = *(const short8*)&lds[(CBA) + arow + (MQ)*4096 + r*1024 + chv0]; \
        a[r][1] = *(const short8*)&lds[(CBA) + arow + (MQ)*4096 + r*1024 + chv1]; \
    }

#define RD_BQ(DST, CBB, NQ)                                                    \
    _Pragma("unroll")                                                          \
    for (int c = 0; c < 2; c++) {                                              \
        DST[c][0] = *(const short8*)&lds[(CBB) + brow + (NQ)*2048 + c*1024 + chv0]; \
        DST[c][1] = *(const short8*)&lds[(CBB) + brow + (NQ)*2048 + c*1024 + chv1]; \
    }

template<int RELU, int OUTM>
__global__ __launch_bounds__(512, 2)
void gemm256(const u16* __restrict__ A, const u16* __restrict__ Bt,
             const float* __restrict__ bias, void* __restrict__ C,
             int M, int N, int K)
{
    // A: [2 dbuf][256][64] @ 0 ; B: [2 dbuf][256][64] @ 32768 (u16 index)
    __shared__ __align__(16) u16 lds[65536];
    const int t = threadIdx.x;
    const int w = t >> 6, l = t & 63;
    const int lane16 = l & 15, quad = l >> 4;
    const int wm = w >> 2, wn = w & 3;          // wave grid: 2 (M) x 4 (N)

    // bijective XCD swizzle (m204)
    const int gx = gridDim.x;
    const int nwg = gx * gridDim.y;
    const int orig = blockIdx.y * gx + blockIdx.x;
    const int q8 = nwg >> 3, r8 = nwg & 7;
    const int xcd = orig & 7, sidx = orig >> 3;
    const int nid = (xcd < r8 ? xcd * (q8 + 1) : r8 * (q8 + 1) + (xcd - r8) * q8) + sidx;
    const int m0 = (nid / gx) * 256;
    const int n0 = (nid % gx) * 256;

    f32x4 acc[8][4];
#pragma unroll
    for (int i = 0; i < 8; i++)
#pragma unroll
        for (int j = 0; j < 4; j++) acc[i][j] = f32x4{0.f, 0.f, 0.f, 0.f};

    // ---- staging setup (rule #21: linear LDS dest, inverse-swizzled source)
    const int lr = l >> 3;                       // lane row within 8-row chunk
    const int xorcol = ((l & 7) ^ lr) * 8;       // logical k-offset (u16) of lane's chunk
    const int aw8 = (w < 4 ? w * 8 : 128 + (w - 4) * 8);
    const u16* Asrc = A + (size_t)(m0 + aw8 + lr) * K + xorcol;
    const u16* Bsrc = Bt + (size_t)(n0 + w * 8 + lr) * K + xorcol;

    auto stageA = [&](int tile, int q) {
        const int c = tile & 1;
        async16(Asrc + (size_t)(q * 32) * K + (tile << 6),
                &lds[c * 16384 + (aw8 + q * 32) * 64]);
    };
    auto stageB = [&](int tile, int j) {
        const int c = tile & 1;
        async16(Bsrc + (size_t)(j * 64) * K + (tile << 6),
                &lds[32768 + c * 16384 + (j * 64 + w * 8) * 64]);
    };

    // ---- ds_read fragment addressing (swizzled): chunk ^= row&7
    const int chv0 = ((0 + quad) ^ (lane16 & 7)) * 8;    // kf = 0
    const int chv1 = ((4 + quad) ^ (lane16 & 7)) * 8;    // kf = 1
    const int arow = (wm * 128 + lane16) * 64;           // + MQ*4096 + r*1024 + chv
    const int brow = (wn * 64 + lane16) * 64;            // + CBB + NQ*2048 + c*1024

    const int NT = K >> 6;        // even (K in {1024, 2048})
    const int niter = NT >> 1;

    // ---- prologue: tile0 (8 calls, oldest), tile1 (8 calls, stays in flight)
    stageA(0, 0); stageA(0, 1); stageA(0, 2); stageA(0, 3);
    stageB(0, 0); stageB(0, 1); stageB(0, 2); stageB(0, 3);
    stageA(1, 0); stageA(1, 1);
    stageB(1, 0); stageB(1, 1); stageB(1, 2); stageB(1, 3);
    stageA(1, 2); stageA(1, 3);
    asm volatile("s_waitcnt vmcnt(8)" ::: "memory");   // tile 0 fully landed
    __builtin_amdgcn_sched_barrier(0);
    __builtin_amdgcn_s_barrier();

    short8 a[4][2], b0[2][2], b1[2][2];

    for (int it = 0; it < niter; it++) {
        const bool hn = (it + 1 < niter);
        const int e2 = 2 * it + 2, o2 = 2 * it + 3;

        // ---------------- K-tile e = 2*it (buf0) ----------------
        // ph1 (m0,n0)
        RD_AQ(0, 0)
        RD_BQ(b0, 32768, 0)
        asm volatile("s_waitcnt lgkmcnt(8)" ::: "memory");
        __builtin_amdgcn_s_barrier();
        LGKM0_FENCE
        MFQ(0, 0, b0)
        __builtin_amdgcn_s_barrier();
        // ph2 (m0,n1)
        RD_BQ(b1, 32768, 1)
        if (hn) { stageA(e2, 0); stageA(e2, 1); }
        __builtin_amdgcn_s_barrier();
        LGKM0_FENCE
        MFQ(0, 1, b1)
        __builtin_amdgcn_s_barrier();
        // ph3 (m1,n0)
        RD_AQ(0, 1)
        if (hn) { stageB(e2, 0); stageB(e2, 1); }
        __builtin_amdgcn_s_barrier();
        LGKM0_FENCE
        MFQ(1, 0, b0)
        __builtin_amdgcn_s_barrier();
        // ph4 (m1,n1): stage rest of e+2; vmcnt(8) retires ALL of tile o
        if (hn) { stageB(e2, 2); stageB(e2, 3); stageA(e2, 2); stageA(e2, 3); }
        __builtin_amdgcn_s_barrier();
        MFQ(1, 1, b1)
        if (hn) asm volatile("s_waitcnt vmcnt(8)" ::: "memory");
        else    asm volatile("s_waitcnt vmcnt(0)" ::: "memory");
        __builtin_amdgcn_sched_barrier(0);
        __builtin_amdgcn_s_barrier();

        // ---------------- K-tile o = 2*it+1 (buf1) ----------------
        // ph5 (m0,n0)
        RD_AQ(16384, 0)
        RD_BQ(b0, 49152, 0)
        asm volatile("s_waitcnt lgkmcnt(8)" ::: "memory");
        __builtin_amdgcn_s_barrier();
        LGKM0_FENCE
        MFQ(0, 0, b0)
        __builtin_amdgcn_s_barrier();
        // ph6 (m0,n1)
        RD_BQ(b1, 49152, 1)
        if (hn) { stageA(o2, 0); stageA(o2, 1); }
        __builtin_amdgcn_s_barrier();
        LGKM0_FENCE
        MFQ(0, 1, b1)
        __builtin_amdgcn_s_barrier();
        // ph7 (m1,n0)
        RD_AQ(16384, 1)
        if (hn) { stageB(o2, 0); stageB(o2, 1); }
        __builtin_amdgcn_s_barrier();
        LGKM0_FENCE
        MFQ(1, 0, b0)
        __builtin_amdgcn_s_barrier();
        // ph8 (m1,n1): stage rest of o+2; vmcnt(8) retires e+2
        if (hn) { stageB(o2, 2); stageB(o2, 3); stageA(o2, 2); stageA(o2, 3); }
        __builtin_amdgcn_s_barrier();
        MFQ(1, 1, b1)
        if (hn) asm volatile("s_waitcnt vmcnt(8)" ::: "memory");
        __builtin_amdgcn_sched_barrier(0);
        __builtin_amdgcn_s_barrier();
    }

    // ---- epilogue
#pragma unroll
    for (int mi = 0; mi < 8; mi++) {
#pragma unroll
        for (int ni = 0; ni < 4; ni++) {
            int col = n0 + wn * 64 + ni * 16 + lane16;
            float bv = bias[col];
            if (OUTM == 2) {
                int tok0 = m0 + wm * 128 + mi * 16 + quad * 4;
                int bb = tok0 >> 9, s0 = tok0 & 511;
                int hh = col >> 6, dd = col & 63;
                u16x4 pk;
#pragma unroll
                for (int r2 = 0; r2 < 4; r2++) pk[r2] = f2bf(acc[mi][ni][r2] + bv);
                *(u16x4*)&((u16*)C)[(((size_t)bb * H_ + hh) * DK_ + dd) * S_ + s0] = pk;
            } else {
                int row = m0 + wm * 128 + mi * 16 + quad * 4;
#pragma unroll
                for (int r2 = 0; r2 < 4; r2++) {
                    float v = acc[mi][ni][r2] + bv;
                    if (RELU) v = fmaxf(v, 0.f);
                    size_t idx = (size_t)(row + r2) * N + col;
                    if (OUTM == 1) ((u16*)C)[idx] = f2bf(v);
                    else           ((float*)C)[idx] = v;
                }
            }
        }
    }
}

// ---------------------------------------------------------------------------
// Barrier-free transposed flash attention, max-free softmax.
// Balanced complementary band pairs (round 8 structure) + VALU-fat removal:
//   (a) hoisted per-lane base pointers kbl/vbl/myPw/myPr — per-load address
//       = base + uniform j0 + compile-time constant (was ~10 VALU 64-bit mul
//       chain per load x16 loads/tile); LDS offsets fold into ds imm.
//   (b) __builtin_amdgcn_exp2f — raw v_exp_f32, 1 inst (exp2(-3e38)=0 keeps
//       masking semantics).
//   (c) diag-split softmax: uniform branch, mask code only on the 1-of-9
//       diagonal tile (was per-element cndmask+index math on every tile).
// ---------------------------------------------------------------------------
#define ATT_TILE(KC, KN)                                                       \
    {                                                                          \
        const int j0 = jt * 64;                                                \
        const bool diag = (jt == ntiles - 1);                                  \
        f32x4 sacc[4][2];                                                      \
        _Pragma("unroll")                                                      \
        for (int ji = 0; ji < 4; ji++)                                         \
            _Pragma("unroll")                                                  \
            for (int ii = 0; ii < 2; ii++)                                     \
                sacc[ji][ii] = f32x4{0.f, 0.f, 0.f, 0.f};                      \
        _Pragma("unroll")                                                      \
        for (int kf = 0; kf < 2; kf++)                                         \
            _Pragma("unroll")                                                  \
            for (int ji = 0; ji < 4; ji++)                                     \
                _Pragma("unroll")                                              \
                for (int ii = 0; ii < 2; ii++)                                 \
                    sacc[ji][ii] = __builtin_amdgcn_mfma_f32_16x16x32_bf16(    \
                        KC[kf][ji], bq[ii][kf], sacc[ji][ii], 0, 0, 0);        \
        short8 aV[2][4];                                                       \
        _Pragma("unroll")                                                      \
        for (int kf = 0; kf < 2; kf++)                                         \
            _Pragma("unroll")                                                  \
            for (int di = 0; di < 4; di++)                                     \
                aV[kf][di] = *(const short8*)(vbl + j0 + di * 8192 + kf * 32); \
        if (!diag) {                                                           \
            _Pragma("unroll")                                                  \
            for (int kf = 0; kf < 2; kf++)                                     \
                _Pragma("unroll")                                              \
                for (int ji = 0; ji < 4; ji++)                                 \
                    KN[kf][ji] = *(const short8*)(kbl + (j0 + 64) * 1024 +     \
                                                  ji * 16384 + kf * 32);       \
        }                                                                      \
        if (diag) {                                                            \
            const int jq0 = j0 + quad * 4;                                     \
            _Pragma("unroll")                                                  \
            for (int ii = 0; ii < 2; ii++) {                                   \
                _Pragma("unroll")                                              \
                for (int ji = 0; ji < 4; ji++) {                               \
                    u16x4 pk;                                                  \
                    _Pragma("unroll")                                          \
                    for (int r2 = 0; r2 < 4; r2++) {                           \
                        float v = sacc[ji][ii][r2] * SC;                       \
                        if (jq0 + ji * 16 + r2 >= iq0 + ii * 16) v = -3e38f;   \
                        float pv = __builtin_amdgcn_exp2f(v);                  \
                        lsum[ii] += pv;                                        \
                        pk[r2] = f2bf_t(pv);                                   \
                    }                                                          \
                    *(u16x4*)&myPw[ii * 1152 + ji * 16] = pk;                  \
                }                                                              \
            }                                                                  \
        } else {                                                               \
            _Pragma("unroll")                                                  \
            for (int ii = 0; ii < 2; ii++) {                                   \
                _Pragma("unroll")                                              \
                for (int ji = 0; ji < 4; ji++) {                               \
                    u16x4 pk;                                                  \
                    _Pragma("unroll")                                          \
                    for (int r2 = 0; r2 < 4; r2++) {                           \
                        float pv = __builtin_amdgcn_exp2f(sacc[ji][ii][r2] * SC); \
                        lsum[ii] += pv;                                        \
                        pk[r2] = f2bf_t(pv);                                   \
                    }                                                          \
                    *(u16x4*)&myPw[ii * 1152 + ji * 16] = pk;                  \
                }                                                              \
            }                                                                  \
        }                                                                      \
        short8 pf[2][2];                                                       \
        _Pragma("unroll")                                                      \
        for (int kf = 0; kf < 2; kf++)                                         \
            _Pragma("unroll")                                                  \
            for (int ii = 0; ii < 2; ii++)                                     \
                pf[kf][ii] = *(const short8*)&myPr[ii * 1152 + kf * 32];       \
        _Pragma("unroll")                                                      \
        for (int kf = 0; kf < 2; kf++)                                         \
            _Pragma("unroll")                                                  \
            for (int di = 0; di < 4; di++)                                     \
                _Pragma("unroll")                                              \
                for (int ii = 0; ii < 2; ii++)                                 \
                    aco[di][ii] = __builtin_amdgcn_mfma_f32_16x16x32_bf16(     \
                        aV[kf][di], pf[kf][ii], aco[di][ii], 0, 0, 0);         \
    }

__global__ __launch_bounds__(256, 2)
void attn_kernel(const u16* __restrict__ qk, const u16* __restrict__ vt,
                 u16* __restrict__ ao)
{
    __shared__ __align__(16) u16 sP[4][32 * 72];
    const int t = threadIdx.x, w = t >> 6, l = t & 63;
    const int lane16 = l & 15, quad = l >> 4;
    // grid 1024: bid = pp*512 + bh; siblings (pp=0/1) differ by 512 ≡ 0 mod 8
    const int bid = blockIdx.x;
    const int pp = bid >> 9;
    const int bh = bid & 511;
    const int b = bh >> 4, h = bh & 15;
    const int bfirst = (pp << 2) | w;           // 0..7
    const u16* kb = qk + (size_t)b * S_ * D_ + h * DK_;
    const u16* vb = vt + (size_t)bh * DK_ * S_;
    u16* aob = ao + (size_t)b * S_ * D_ + h * DK_;
    const float SC = 0.125f * 1.44269504f;  // (1/sqrt(DK)) * log2(e)

    // hoisted per-lane bases (all per-load addresses = base + j0 + const)
    const u16* kbl = kb + lane16 * D_ + quad * 8;      // K row stride D_=1024
    const u16* vbl = vb + lane16 * S_ + quad * 8;      // V^T row stride S_=512
    u16* myPw = sP[w] + lane16 * 72 + quad * 4;        // P write base
    const u16* myPr = sP[w] + lane16 * 72 + quad * 8;  // P read base

    for (int half = 0; half < 2; half++) {
        const int band = half == 0 ? bfirst : 15 - bfirst;
        const int band0 = band * 32;
        const int ntiles = (band >> 1) + 1;
        const int iq0 = band0 + lane16;                // i index base (diag mask)

        short8 bq[2][2];
#pragma unroll
        for (int ii = 0; ii < 2; ii++)
#pragma unroll
            for (int kf = 0; kf < 2; kf++)
                bq[ii][kf] = *(const short8*)(kbl + band0 * 1024 + ii * 16384 + kf * 32);

        f32x4 aco[4][2];
        float lsum[2] = {0.f, 0.f};
#pragma unroll
        for (int di = 0; di < 4; di++)
#pragma unroll
            for (int ii = 0; ii < 2; ii++) aco[di][ii] = f32x4{0.f, 0.f, 0.f, 0.f};

        short8 aKa[2][4], aKb[2][4];
        // preload K tile 0 into aKa
#pragma unroll
        for (int kf = 0; kf < 2; kf++)
#pragma unroll
            for (int ji = 0; ji < 4; ji++)
                aKa[kf][ji] = *(const short8*)(kbl + ji * 16384 + kf * 32);

        int jt = 0;
        for (;;) {
            ATT_TILE(aKa, aKb)
            if (++jt >= ntiles) break;
            ATT_TILE(aKb, aKa)
            if (++jt >= ntiles) break;
        }

        // fold partial denominators across the 4 quads (replicated per i)
#pragma unroll
        for (int ii = 0; ii < 2; ii++) {
            lsum[ii] += __shfl_xor(lsum[ii], 16);
            lsum[ii] += __shfl_xor(lsum[ii], 32);
        }

        // write O (O^T layout: i=lane16, d=quad*4+r2); row 0 zeroed (zero_pad)
#pragma unroll
        for (int ii = 0; ii < 2; ii++) {
            int row = band0 + ii * 16 + lane16;
            float lv = lsum[ii];
            float inv = (row == 0 || !(lv > 0.f)) ? 0.f : 1.f / lv;
#pragma unroll
            for (int di = 0; di < 4; di++) {
                u16x4 o;
#pragma unroll
                for (int r2 = 0; r2 < 4; r2++) o[r2] = f2bf(aco[di][ii][r2] * inv);
                *(u16x4*)&aob[(size_t)row * D_ + di * 16 + quad * 4] = o;
            }
        }
    }
}

// ---------------------------------------------------------------------------
// Fused residual + LayerNorm. (unchanged)
// ---------------------------------------------------------------------------
template<int XBF, int WF32>
__global__ __launch_bounds__(256)
void ln_kernel(const void* __restrict__ xin, const float* __restrict__ addv,
               const float* __restrict__ sc, const float* __restrict__ bi,
               u16* __restrict__ xb_out, float* __restrict__ f32_out)
{
    const int row = blockIdx.x;
    const int t = threadIdx.x;
    const int w = t >> 6, l = t & 63;
    __shared__ float red[8];
    f32x4 a;
    if (XBF) {
        u16x4 raw = ((const u16x4*)xin)[(size_t)row * 256 + t];
#pragma unroll
        for (int j = 0; j < 4; j++) a[j] = bf2f(raw[j]);
    } else {
        a = ((const f32x4*)xin)[(size_t)row * 256 + t];
    }
    f32x4 c = ((const f32x4*)(addv + (size_t)row * D_))[t];
    f32x4 v;
    float s1 = 0.f, s2 = 0.f;
#pragma unroll
    for (int j = 0; j < 4; j++) {
        v[j] = a[j] + c[j];
        s1 += v[j];
        s2 += v[j] * v[j];
    }
#pragma unroll
    for (int off = 32; off > 0; off >>= 1) {
        s1 += __shfl_xor(s1, off);
        s2 += __shfl_xor(s2, off);
    }
    if (l == 0) { red[w * 2] = s1; red[w * 2 + 1] = s2; }
    __syncthreads();
    s1 = red[0] + red[2] + red[4] + red[6];
    s2 = red[1] + red[3] + red[5] + red[7];
    float mean = s1 * (1.f / D_);
    float var = s2 * (1.f / D_) - mean * mean;
    float rstd = rsqrtf(var + 1e-5f);
    f32x4 s4 = ((const f32x4*)sc)[t];
    f32x4 b4 = ((const f32x4*)bi)[t];
    f32x4 o;
    u16x4 ob;
#pragma unroll
    for (int j = 0; j < 4; j++) {
        o[j] = (v[j] - mean) * rstd * s4[j] + b4[j];
        ob[j] = f2bf(o[j]);
    }
    ((u16x4*)(xb_out + (size_t)row * D_))[t] = ob;
    if (WF32) ((f32x4*)(f32_out + (size_t)row * D_))[t] = o;
}

// fp32 -> bf16 convert
__global__ void cvt_kernel(const float* __restrict__ in, u16* __restrict__ out, int n4)
{
    int i = blockIdx.x * blockDim.x + threadIdx.x;
    if (i < n4) {
        f32x4 v = ((const f32x4*)in)[i];
        u16x4 o;
#pragma unroll
        for (int j = 0; j < 4; j++) o[j] = f2bf(v[j]);
        ((u16x4*)out)[i] = o;
    }
}

// W[K,N] fp32 -> WT[N,K] bf16, 64x64 tiles
__device__ __forceinline__ void tconv_body(const float* W, u16* WT, int K, int N,
                                           int bx, int by, int t)
{
    __shared__ float tile[64][65];
    const int n0 = bx * 64, k0 = by * 64;
#pragma unroll
    for (int i = 0; i < 4; i++) {
        int kr = (t >> 4) + i * 16;
        int nc = (t & 15) * 4;
        f32x4 v = *(const f32x4*)&W[(size_t)(k0 + kr) * N + n0 + nc];
        tile[kr][nc] = v[0]; tile[kr][nc + 1] = v[1];
        tile[kr][nc + 2] = v[2]; tile[kr][nc + 3] = v[3];
    }
    __syncthreads();
#pragma unroll
    for (int i = 0; i < 4; i++) {
        int nr = (t >> 4) + i * 16;
        int kc = (t & 15) * 4;
        u16x4 o;
#pragma unroll
        for (int j = 0; j < 4; j++) o[j] = f2bf(tile[kc + j][nr]);
        *(u16x4*)&WT[(size_t)(n0 + nr) * K + k0 + kc] = o;
    }
}

// all 5 per-layer weights in one dispatch: 3*256 + 512 + 512 = 1792 tiles
__global__ __launch_bounds__(256)
void wconv_kernel(const float* __restrict__ Wk, const float* __restrict__ Wv,
                  const float* __restrict__ Wo, const float* __restrict__ W1f,
                  const float* __restrict__ W2f,
                  u16* __restrict__ wk, u16* __restrict__ wv, u16* __restrict__ wo,
                  u16* __restrict__ w1, u16* __restrict__ w2)
{
    const int idx = blockIdx.x;
    const float* W; u16* T; int K, N, bx, by;
    if (idx < 768) {
        int wsel = idx >> 8, t16 = idx & 255;
        W = (wsel == 0) ? Wk : (wsel == 1) ? Wv : Wo;
        T = (wsel == 0) ? wk : (wsel == 1) ? wv : wo;
        K = 1024; N = 1024; bx = t16 & 15; by = t16 >> 4;
    } else if (idx < 1280) {
        int i = idx - 768;
        W = W1f; T = w1; K = 1024; N = 2048; bx = i & 31; by = i >> 5;
    } else {
        int i = idx - 1280;
        W = W2f; T = w2; K = 2048; N = 1024; bx = i & 15; by = i >> 4;
    }
    tconv_body(W, T, K, N, bx, by, threadIdx.x);
}

extern "C" void kernel_launch(void* const* d_in, const int* in_sizes, int n_in,
                              void* d_out, int out_size, void* d_ws, size_t ws_size,
                              hipStream_t stream)
{
    const float* q_embed = (const float*)d_in[0];
    const float* qa_embed = (const float*)d_in[1];
    const float* Wk = (const float*)d_in[2];
    const float* bk = (const float*)d_in[3];
    const float* Wv = (const float*)d_in[4];
    const float* bv = (const float*)d_in[5];
    const float* Wo = (const float*)d_in[6];
    const float* bo = (const float*)d_in[7];
    const float* ln1_s = (const float*)d_in[8];
    const float* ln1_b = (const float*)d_in[9];
    const float* W1 = (const float*)d_in[10];
    const float* b1 = (const float*)d_in[11];
    const float* W2 = (const float*)d_in[12];
    const float* b2 = (const float*)d_in[13];
    const float* ln2_s = (const float*)d_in[14];
    const float* ln2_b = (const float*)d_in[15];
    (void)in_sizes; (void)n_in; (void)out_size;

    char* ws = (char*)d_ws;
    size_t off = 0;
    auto carve = [&](size_t bytes) -> char* {
        char* p = ws + off;
        off += (bytes + 255) & ~(size_t)255;
        return p;
    };
    const size_t NTOK = (size_t)B_ * S_;  // 16384
    u16* wk = (u16*)carve((size_t)D_ * D_ * 2);
    u16* wv = (u16*)carve((size_t)D_ * D_ * 2);
    u16* wo = (u16*)carve((size_t)D_ * D_ * 2);
    u16* w1 = (u16*)carve((size_t)D_ * DFF_ * 2);
    u16* w2 = (u16*)carve((size_t)DFF_ * D_ * 2);
    u16* x = (u16*)carve(NTOK * D_ * 2);           // bf16 residual master
    u16* U12 = (u16*)carve(NTOK * DFF_ * 2);       // [qkb | vbf] then hb
    u16* U3 = (u16*)carve(NTOK * D_ * 2);          // aob (and ybf in overlay mode)
    size_t off_overlay = off;
    u16* ybf_sep = (u16*)carve(NTOK * D_ * 2);
    bool sep = (ws_size >= off);
    if (!sep) off = off_overlay;
    if (ws_size < off) return;

    u16* qkb = U12;
    u16* vbf = U12 + NTOK * D_;   // V^T [b,h,d,s]
    u16* hb = U12;
    u16* aob = U3;
    u16* ybf = sep ? ybf_sep : U3;
    float* of32 = (float*)d_out;  // fp32 scratch: attn-o / ffn2 outputs

    cvt_kernel<<<16384, 256, 0, stream>>>(q_embed, x, (int)(NTOK * D_ / 4));
    if (sep)
        cvt_kernel<<<16384, 256, 0, stream>>>(qa_embed, ybf, (int)(NTOK * D_ / 4));

    const dim3 G1024(4, 64), G2048(8, 64);   // 256x256 output tiles
    for (int lyr = 0; lyr < L_; lyr++) {
        const size_t wsq = (size_t)lyr * D_ * D_;
        const size_t wf1 = (size_t)lyr * D_ * DFF_;
        wconv_kernel<<<1792, 256, 0, stream>>>(Wk + wsq, Wv + wsq, Wo + wsq,
                                               W1 + wf1, W2 + wf1,
                                               wk, wv, wo, w1, w2);
        if (!sep)
            cvt_kernel<<<16384, 256, 0, stream>>>(qa_embed, ybf, (int)(NTOK * D_ / 4));
        // qk = x @ Wk + bk (bf16, row-major; serves as Q and K)
        gemm256<0, 1><<<G1024, 512, 0, stream>>>(x, wk, bk + lyr * D_,
                                                 qkb, (int)NTOK, D_, D_);
        // v = y @ Wv + bv, written directly as V^T [b,h,d,s]
        gemm256<0, 2><<<G1024, 512, 0, stream>>>(ybf, wv, bv + lyr * D_,
                                                 vbf, (int)NTOK, D_, D_);
        // balanced barrier-free transposed causal attention (9 tiles/wave)
        attn_kernel<<<1024, 256, 0, stream>>>(qkb, vbf, aob);
        // o = attn_out @ Wo + bo (fp32 into d_out scratch)
        gemm256<0, 0><<<G1024, 512, 0, stream>>>(aob, wo, bo + lyr * D_,
                                                 of32, (int)NTOK, D_, D_);
        // x = LN1(x + o)
        if (lyr == 0)
            ln_kernel<0, 0><<<(int)NTOK, 256, 0, stream>>>(q_embed, of32,
                ln1_s + lyr * D_, ln1_b + lyr * D_, x, nullptr);
        else
            ln_kernel<1, 0><<<(int)NTOK, 256, 0, stream>>>(x, of32,
                ln1_s + lyr * D_, ln1_b + lyr * D_, x, nullptr);
        // h = relu(x @ W1 + b1)
        gemm256<1, 1><<<G2048, 512, 0, stream>>>(x, w1, b1 + lyr * DFF_,
                                                 hb, (int)NTOK, DFF_, D_);
        // f = h @ W2 + b2 (fp32 into d_out scratch)
        gemm256<0, 0><<<G1024, 512, 0, stream>>>(hb, w2, b2 + lyr * D_,
                                                 of32, (int)NTOK, D_, DFF_);
        // x = LN2(x + f); final layer also writes fp32 d_out
        if (lyr == L_ - 1)
            ln_kernel<1, 1><<<(int)NTOK, 256, 0, stream>>>(x, of32,
                ln2_s + lyr * D_, ln2_b + lyr * D_, x, (float*)d_out);
        else
            ln_kernel<1, 0><<<(int)NTOK, 256, 0, stream>>>(x, of32,
                ln2_s + lyr * D_, ln2_b + lyr * D_, x, nullptr);
    }
}